// Round 6
// baseline (379.591 us; speedup 1.0000x reference)
//
#include <hip/hip_runtime.h>
#include <math.h>

#define NV 50000
#define ETR 800000
#define EPOS 200000
#define ETEST 400000

typedef __attribute__((ext_vector_type(8))) short bf16x8;
typedef __attribute__((ext_vector_type(8))) unsigned short ushortx8;
typedef __attribute__((ext_vector_type(4))) float f32x4;

__device__ inline unsigned short f2b(float f) {
    union { float f; unsigned u; } v; v.f = f;
    unsigned r = v.u + 0x7fffu + ((v.u >> 16) & 1u);   // RNE
    return (unsigned short)(r >> 16);
}
__device__ inline float blo(unsigned q) { union { unsigned u; float f; } v; v.u = q << 16; return v.f; }
__device__ inline float bhi(unsigned q) { union { unsigned u; float f; } v; v.u = q & 0xffff0000u; return v.f; }
__device__ inline float b2f(unsigned short s) { union { unsigned u; float f; } v; v.u = ((unsigned)s) << 16; return v.f; }

__device__ inline ushortx8 bf16add8(ushortx8 a, ushortx8 b) {
    ushortx8 r;
    #pragma unroll
    for (int i = 0; i < 8; ++i)
        r[i] = f2b(b2f(a[i]) + b2f(b[i]));
    return r;
}

// ---------------- CSR build ----------------

__global__ void deg_kernel(const int* __restrict__ tei, int* __restrict__ deg) {
    int e = blockIdx.x * blockDim.x + threadIdx.x;
    if (e < ETR) atomicAdd(&deg[tei[ETR + e]], 1);
}

__global__ __launch_bounds__(1024) void partial_kernel(const int* __restrict__ deg,
                                                       int* __restrict__ partials) {
    int i = blockIdx.x * 1024 + threadIdx.x;
    int v = (i < NV) ? deg[i] : 0;
    #pragma unroll
    for (int off = 32; off > 0; off >>= 1) v += __shfl_xor(v, off);
    __shared__ int wsum[16];
    if ((threadIdx.x & 63) == 0) wsum[threadIdx.x >> 6] = v;
    __syncthreads();
    if (threadIdx.x == 0) {
        int s = 0;
        #pragma unroll
        for (int k = 0; k < 16; ++k) s += wsum[k];
        partials[blockIdx.x] = s;
    }
}

__global__ __launch_bounds__(1024) void ptr_kernel(
    const int* __restrict__ deg, const int* __restrict__ partials,
    int* __restrict__ ptr, int* __restrict__ cursor, float* __restrict__ dinv)
{
    int b = blockIdx.x, t = threadIdx.x;
    int i = b * 1024 + t;
    int d = (i < NV) ? deg[i] : 0;
    int lane = t & 63, w = t >> 6;
    int v = d;
    #pragma unroll
    for (int off = 1; off < 64; off <<= 1) {
        int u = __shfl_up(v, off);
        if (lane >= off) v += u;
    }
    __shared__ int wsum[16], woff[16];
    if (lane == 63) wsum[w] = v;
    __syncthreads();
    if (t == 0) {
        int s = 0;
        for (int k = 0; k < b; ++k) s += partials[k];
        for (int k = 0; k < 16; ++k) { woff[k] = s; s += wsum[k]; }
    }
    __syncthreads();
    int excl = woff[w] + v - d;
    if (i < NV) {
        ptr[i] = excl;
        cursor[i] = excl;
        dinv[i] = rsqrtf((float)d + 2.0f);   // SELF_LOOP_W = 2
        if (i == NV - 1) ptr[NV] = excl + d;
    }
}

// edat[p] = (source row, norm = dinv[row]*dinv[col]) — kills the dependent dinv load in gather
__global__ void fill_kernel(const int* __restrict__ tei, const float* __restrict__ dinv,
                            int* __restrict__ cursor, int2* __restrict__ edat) {
    int e = blockIdx.x * blockDim.x + threadIdx.x;
    if (e < ETR) {
        int row = tei[e];
        int col = tei[ETR + e];
        int p = atomicAdd(&cursor[col], 1);
        edat[p] = make_int2(row, __float_as_int(dinv[row] * dinv[col]));
    }
}

// ---------------- converts ----------------

__global__ void cvt_x_kernel(const float* __restrict__ x, unsigned short* __restrict__ xb, int n4) {
    int i = blockIdx.x * blockDim.x + threadIdx.x;
    if (i < n4) {
        float4 v = *(const float4*)&x[i * 4];
        union { unsigned short u[4]; uint2 q; } o;
        o.u[0] = f2b(v.x); o.u[1] = f2b(v.y); o.u[2] = f2b(v.z); o.u[3] = f2b(v.w);
        *(uint2*)&xb[i * 4] = o.q;
    }
}

// Wt[n][k] = bf16(W[k][n])
__global__ void cvt_wt_kernel(const float* __restrict__ W, unsigned short* __restrict__ Wt,
                              int K, int N) {
    int idx = blockIdx.x * blockDim.x + threadIdx.x;
    if (idx < N * K) {
        int n = idx / K, k = idx - n * K;
        Wt[idx] = f2b(W[k * N + n]);
    }
}

// ---------------- bf16 MFMA GEMM: C[M][N] = A[M][K] @ Bt[N][K]^T ----------------
// 128x128 tile, 4 waves in 2x2, BK=64, 16x16x32 MFMA, XOR-swizzled LDS (T2).

template<int N, int K, bool OUTBF>
__global__ __launch_bounds__(256) void mfma_gemm_kernel(
    const unsigned short* __restrict__ A, const unsigned short* __restrict__ Bt,
    void* __restrict__ Cv, int M)
{
    constexpr int BK = 64;
    __shared__ unsigned short Asm[128][BK];
    __shared__ unsigned short Bsm[128][BK];
    int tid = threadIdx.x;
    int lane = tid & 63, wid = tid >> 6;
    int wr = wid >> 1, wc = wid & 1;
    int row0 = blockIdx.x * 128, col0 = blockIdx.y * 128;

    int sr = tid >> 3;
    int s8 = tid & 7;
    int sswz = s8 ^ (sr & 7);
    int fr = lane & 15;
    int g  = lane >> 4;

    f32x4 acc[4][4] = {};

    for (int k0 = 0; k0 < K; k0 += BK) {
        #pragma unroll
        for (int i = 0; i < 4; ++i) {
            int r = sr + i * 32;
            int gr = row0 + r;
            ushortx8 va = {0, 0, 0, 0, 0, 0, 0, 0};
            if (gr < M) va = *(const ushortx8*)&A[(size_t)gr * K + k0 + s8 * 8];
            *(ushortx8*)&Asm[r][sswz * 8] = va;
            ushortx8 vb = *(const ushortx8*)&Bt[(size_t)(col0 + r) * K + k0 + s8 * 8];
            *(ushortx8*)&Bsm[r][sswz * 8] = vb;
        }
        __syncthreads();
        #pragma unroll
        for (int kf = 0; kf < BK; kf += 32) {
            int sbase = kf >> 3;
            bf16x8 af[4], bfr[4];
            #pragma unroll
            for (int m = 0; m < 4; ++m) {
                int rr = wr * 64 + m * 16 + fr;
                af[m] = *(const bf16x8*)&Asm[rr][((sbase + g) ^ (fr & 7)) * 8];
            }
            #pragma unroll
            for (int n = 0; n < 4; ++n) {
                int rr = wc * 64 + n * 16 + fr;
                bfr[n] = *(const bf16x8*)&Bsm[rr][((sbase + g) ^ (fr & 7)) * 8];
            }
            #pragma unroll
            for (int m = 0; m < 4; ++m)
                #pragma unroll
                for (int n = 0; n < 4; ++n)
                    acc[m][n] = __builtin_amdgcn_mfma_f32_16x16x32_bf16(af[m], bfr[n], acc[m][n], 0, 0, 0);
        }
        __syncthreads();
    }

    // C/D layout: col = lane&15, row = (lane>>4)*4 + j
    #pragma unroll
    for (int m = 0; m < 4; ++m) {
        int rbase = row0 + wr * 64 + m * 16 + g * 4;
        #pragma unroll
        for (int j = 0; j < 4; ++j) {
            int r = rbase + j;
            if (r < M) {
                #pragma unroll
                for (int n = 0; n < 4; ++n) {
                    int c = col0 + wc * 64 + n * 16 + fr;
                    float v = acc[m][n][j];
                    if constexpr (OUTBF)
                        ((unsigned short*)Cv)[(size_t)r * N + c] = f2b(v);
                    else
                        ((float*)Cv)[(size_t)r * N + c] = v;
                }
            }
        }
    }
}

// ---------------- feature-sliced gather ----------------
// slice = 32 bf16 (64B rows, 3.2MB working set -> fits one XCD's 4MB L2).
// slice = blockIdx % NSLICE pins each slice to XCD(s) under round-robin dispatch.
// Wave = 4 nodes x 16 lanes, 2 feats (uint) per lane. edat gives (row, norm) in
// one sequential 8B broadcast load; only the 64B row read is random.

template<int F, bool RELU>
__global__ __launch_bounds__(256) void gather_slice_kernel(
    const int* __restrict__ ptr, const int2* __restrict__ edat,
    const float* __restrict__ dinv, const unsigned short* __restrict__ hlin,
    const float* __restrict__ bias, unsigned short* __restrict__ hout)
{
    constexpr int NSLICE = F / 32;
    int slice = blockIdx.x & (NSLICE - 1);
    int nb = blockIdx.x / NSLICE;
    int tid = threadIdx.x;
    int lane = tid & 63;
    int node = nb * 16 + (tid >> 6) * 4 + (lane >> 4);
    int fl = lane & 15;
    int co = slice * 32 + fl * 2;
    const unsigned short* hcol = hlin + co;
    float dc = dinv[node];
    int j0 = ptr[node], j1 = ptr[node + 1];
    float a0 = 0.f, a1 = 0.f;
    int j = j0;
    for (; j + 1 < j1; j += 2) {
        int2 e0 = edat[j];
        int2 e1 = edat[j + 1];
        float n0 = __int_as_float(e0.y);
        float n1 = __int_as_float(e1.y);
        unsigned q0 = *(const unsigned*)&hcol[(size_t)e0.x * F];
        unsigned q1 = *(const unsigned*)&hcol[(size_t)e1.x * F];
        a0 += n0 * blo(q0) + n1 * blo(q1);
        a1 += n0 * bhi(q0) + n1 * bhi(q1);
    }
    if (j < j1) {
        int2 e0 = edat[j];
        float n0 = __int_as_float(e0.y);
        unsigned q0 = *(const unsigned*)&hcol[(size_t)e0.x * F];
        a0 += n0 * blo(q0);
        a1 += n0 * bhi(q0);
    }
    // self-loop (weight 2, norm dc^2) + bias (+relu)
    unsigned qs = *(const unsigned*)&hcol[(size_t)node * F];
    float sw = 2.0f * dc * dc;
    float2 bv = *(const float2*)&bias[co];
    float o0 = a0 + sw * blo(qs) + bv.x;
    float o1 = a1 + sw * bhi(qs) + bv.y;
    if (RELU) { o0 = fmaxf(o0, 0.f); o1 = fmaxf(o1, 0.f); }
    union { unsigned short u[2]; unsigned q; } pk;
    pk.u[0] = f2b(o0); pk.u[1] = f2b(o1);
    *(unsigned*)&hout[(size_t)node * F + co] = pk.q;
}

// ---------------- edge MLP via MFMA ----------------

__global__ __launch_bounds__(256) void edge_mlp_mfma_kernel(
    const int* __restrict__ pos, const int* __restrict__ neg,
    const unsigned short* __restrict__ h2, const unsigned short* __restrict__ Wl1t,
    const float* __restrict__ bl1, const float* __restrict__ Wl2,
    const float* __restrict__ bl2, float* __restrict__ out)
{
    __shared__ unsigned short Es[128][128];
    __shared__ unsigned short Ws[64][128];
    int tid = threadIdx.x;
    int lane = tid & 63, w = tid >> 6;
    int fr = lane & 15, g = lane >> 4;
    int e0 = blockIdx.x * 128;

    #pragma unroll
    for (int k = 0; k < 4; ++k) {
        int chunk = tid + k * 256;
        int row = chunk >> 4, c = chunk & 15;
        *(ushortx8*)&Ws[row][(c ^ (row & 7)) * 8] = *(const ushortx8*)&Wl1t[chunk * 8];
    }

    int et = tid >> 1, hh = tid & 1;
    int eg = e0 + et;
    int a, b;
    if (eg < EPOS) { a = pos[eg]; b = pos[EPOS + eg]; }
    else { int i = eg - EPOS; a = neg[i]; b = neg[EPOS + i]; }
    const unsigned short* pa = h2 + (size_t)a * 128 + hh * 64;
    const unsigned short* pb = h2 + (size_t)b * 128 + hh * 64;
    #pragma unroll
    for (int c8 = 0; c8 < 8; ++c8) {
        ushortx8 va = *(const ushortx8*)&pa[c8 * 8];
        ushortx8 vb = *(const ushortx8*)&pb[c8 * 8];
        ushortx8 vs = bf16add8(va, vb);
        int c = hh * 8 + c8;
        *(ushortx8*)&Es[et][(c ^ (et & 7)) * 8] = vs;
    }
    __syncthreads();

    f32x4 acc[2][4] = {};
    #pragma unroll
    for (int ks = 0; ks < 4; ++ks) {
        int c = ks * 4 + g;
        bf16x8 af[2], bfr[4];
        #pragma unroll
        for (int m = 0; m < 2; ++m) {
            int r = w * 32 + m * 16 + fr;
            af[m] = *(const bf16x8*)&Es[r][(c ^ (r & 7)) * 8];
        }
        #pragma unroll
        for (int n = 0; n < 4; ++n) {
            int r = n * 16 + fr;
            bfr[n] = *(const bf16x8*)&Ws[r][(c ^ (r & 7)) * 8];
        }
        #pragma unroll
        for (int m = 0; m < 2; ++m)
            #pragma unroll
            for (int n = 0; n < 4; ++n)
                acc[m][n] = __builtin_amdgcn_mfma_f32_16x16x32_bf16(af[m], bfr[n], acc[m][n], 0, 0, 0);
    }

    float bl2v = bl2[0];
    float b1v[4], w2v[4];
    #pragma unroll
    for (int n = 0; n < 4; ++n) {
        b1v[n] = bl1[n * 16 + fr];
        w2v[n] = Wl2[n * 16 + fr];
    }
    #pragma unroll
    for (int m = 0; m < 2; ++m) {
        float p[4];
        #pragma unroll
        for (int j = 0; j < 4; ++j) {
            float s = 0.f;
            #pragma unroll
            for (int n = 0; n < 4; ++n)
                s += fmaxf(acc[m][n][j] + b1v[n], 0.0f) * w2v[n];
            p[j] = s;
        }
        #pragma unroll
        for (int off = 1; off < 16; off <<= 1) {
            #pragma unroll
            for (int j = 0; j < 4; ++j)
                p[j] += __shfl_xor(p[j], off);
        }
        int ebase = e0 + w * 32 + m * 16 + g * 4;
        #pragma unroll
        for (int j = 0; j < 4; ++j)
            if (fr == j)
                out[ebase + j] = 1.0f / (1.0f + expf(-(p[j] + bl2v)));
    }
}

// ---------------- launch ----------------

extern "C" void kernel_launch(void* const* d_in, const int* in_sizes, int n_in,
                              void* d_out, int out_size, void* d_ws, size_t ws_size,
                              hipStream_t stream) {
    const float* x   = (const float*)d_in[0];
    const int*   tei = (const int*)d_in[1];
    const int*   pos = (const int*)d_in[2];
    const int*   neg = (const int*)d_in[3];
    const float* W1  = (const float*)d_in[4];
    const float* b1  = (const float*)d_in[5];
    const float* W2  = (const float*)d_in[6];
    const float* b2  = (const float*)d_in[7];
    const float* Wl1 = (const float*)d_in[8];
    const float* bl1 = (const float*)d_in[9];
    const float* Wl2 = (const float*)d_in[10];
    const float* bl2 = (const float*)d_in[11];
    float* out = (float*)d_out;

    // workspace (4B-word offsets, total ~84.2MB; round 1 proved >=106MB available)
    float* fws = (float*)d_ws;
    int*   iws = (int*)d_ws;
    unsigned short* usws = (unsigned short*)d_ws;
    float* dinv     = fws;                         // [50000]
    int*   deg      = iws + 50000;                 // [50000]
    int*   ptr      = iws + 100000;                // [50001]
    int*   cursor   = iws + 150002;                // [50000]
    int2*  edat     = (int2*)(iws + 200064);       // [800000] int2 -> ends 1800064
    int*   partials = iws + 1800064;               // [64]
    unsigned short* w1t  = usws + 2ull * 1800192;  // [256*256] -> ends 1832960
    unsigned short* w2t  = usws + 2ull * 1832960;  // [128*256] -> ends 1849344
    unsigned short* wl1t = usws + 2ull * 1849344;  // [64*128]  -> ends 1853440
    unsigned short* bufX = usws + 2ull * 1853504;  // 12.8M ushorts: xb, then h2lin
    unsigned short* bufL16 = usws + 2ull * 8253504;  // h1lin bf16, then h2 bf16
    unsigned short* bufH = usws + 2ull * 14653504;   // h1 bf16 (ends 21053504 w = 84.2MB)

    hipMemsetAsync(deg, 0, NV * sizeof(int), stream);

    deg_kernel<<<(ETR + 255) / 256, 256, 0, stream>>>(tei, deg);
    partial_kernel<<<49, 1024, 0, stream>>>(deg, partials);
    ptr_kernel<<<49, 1024, 0, stream>>>(deg, partials, ptr, cursor, dinv);
    fill_kernel<<<(ETR + 255) / 256, 256, 0, stream>>>(tei, dinv, cursor, edat);

    cvt_x_kernel<<<(NV * 256 / 4 + 255) / 256, 256, 0, stream>>>(x, bufX, NV * 256 / 4);
    cvt_wt_kernel<<<(256 * 256 + 255) / 256, 256, 0, stream>>>(W1, w1t, 256, 256);
    cvt_wt_kernel<<<(128 * 256 + 255) / 256, 256, 0, stream>>>(W2, w2t, 256, 128);
    cvt_wt_kernel<<<(64 * 128 + 255) / 256, 256, 0, stream>>>(Wl1, wl1t, 128, 64);

    // layer 1
    mfma_gemm_kernel<256, 256, true><<<dim3(391, 2), 256, 0, stream>>>(bufX, w1t, bufL16, NV);
    gather_slice_kernel<256, true><<<3125 * 8, 256, 0, stream>>>(ptr, edat, dinv, bufL16, b1, bufH);

    // layer 2 (h2lin overwrites bufX; h2 bf16 overwrites bufL16)
    mfma_gemm_kernel<128, 256, true><<<dim3(391, 1), 256, 0, stream>>>(bufH, w2t, bufX, NV);
    gather_slice_kernel<128, false><<<3125 * 4, 256, 0, stream>>>(ptr, edat, dinv, bufX, b2, bufL16);

    // edge MLP head (MFMA)
    edge_mlp_mfma_kernel<<<ETEST / 128, 256, 0, stream>>>(pos, neg, bufL16, wl1t, bl1, Wl2, bl2, out);
}

// Round 7
// 300.122 us; speedup vs baseline: 1.2648x; 1.2648x over previous
//
#include <hip/hip_runtime.h>
#include <math.h>

#define NV 50000
#define ETR 800000
#define EPOS 200000
#define ETEST 400000

typedef __attribute__((ext_vector_type(8))) short bf16x8;
typedef __attribute__((ext_vector_type(8))) unsigned short ushortx8;
typedef __attribute__((ext_vector_type(4))) float f32x4;

__device__ inline unsigned short f2b(float f) {
    union { float f; unsigned u; } v; v.f = f;
    unsigned r = v.u + 0x7fffu + ((v.u >> 16) & 1u);   // RNE
    return (unsigned short)(r >> 16);
}
__device__ inline float blo(unsigned q) { union { unsigned u; float f; } v; v.u = q << 16; return v.f; }
__device__ inline float bhi(unsigned q) { union { unsigned u; float f; } v; v.u = q & 0xffff0000u; return v.f; }
__device__ inline float b2f(unsigned short s) { union { unsigned u; float f; } v; v.u = ((unsigned)s) << 16; return v.f; }

__device__ inline ushortx8 bf16add8(ushortx8 a, ushortx8 b) {
    ushortx8 r;
    #pragma unroll
    for (int i = 0; i < 8; ++i)
        r[i] = f2b(b2f(a[i]) + b2f(b[i]));
    return r;
}

// ---------------- CSR build ----------------

__global__ void deg_kernel(const int* __restrict__ tei, int* __restrict__ deg) {
    int e = blockIdx.x * blockDim.x + threadIdx.x;
    if (e < ETR) atomicAdd(&deg[tei[ETR + e]], 1);
}

__global__ __launch_bounds__(1024) void partial_kernel(const int* __restrict__ deg,
                                                       int* __restrict__ partials) {
    int i = blockIdx.x * 1024 + threadIdx.x;
    int v = (i < NV) ? deg[i] : 0;
    #pragma unroll
    for (int off = 32; off > 0; off >>= 1) v += __shfl_xor(v, off);
    __shared__ int wsum[16];
    if ((threadIdx.x & 63) == 0) wsum[threadIdx.x >> 6] = v;
    __syncthreads();
    if (threadIdx.x == 0) {
        int s = 0;
        #pragma unroll
        for (int k = 0; k < 16; ++k) s += wsum[k];
        partials[blockIdx.x] = s;
    }
}

__global__ __launch_bounds__(1024) void ptr_kernel(
    const int* __restrict__ deg, const int* __restrict__ partials,
    int* __restrict__ ptr, int* __restrict__ cursor, float* __restrict__ dinv)
{
    int b = blockIdx.x, t = threadIdx.x;
    int i = b * 1024 + t;
    int d = (i < NV) ? deg[i] : 0;
    int lane = t & 63, w = t >> 6;
    int v = d;
    #pragma unroll
    for (int off = 1; off < 64; off <<= 1) {
        int u = __shfl_up(v, off);
        if (lane >= off) v += u;
    }
    __shared__ int wsum[16], woff[16];
    if (lane == 63) wsum[w] = v;
    __syncthreads();
    if (t == 0) {
        int s = 0;
        for (int k = 0; k < b; ++k) s += partials[k];
        for (int k = 0; k < 16; ++k) { woff[k] = s; s += wsum[k]; }
    }
    __syncthreads();
    int excl = woff[w] + v - d;
    if (i < NV) {
        ptr[i] = excl;
        cursor[i] = excl;
        dinv[i] = rsqrtf((float)d + 2.0f);   // SELF_LOOP_W = 2
        if (i == NV - 1) ptr[NV] = excl + d;
    }
}

// edat[p] = (source row, norm = dinv[row]*dinv[col])
__global__ void fill_kernel(const int* __restrict__ tei, const float* __restrict__ dinv,
                            int* __restrict__ cursor, int2* __restrict__ edat) {
    int e = blockIdx.x * blockDim.x + threadIdx.x;
    if (e < ETR) {
        int row = tei[e];
        int col = tei[ETR + e];
        int p = atomicAdd(&cursor[col], 1);
        edat[p] = make_int2(row, __float_as_int(dinv[row] * dinv[col]));
    }
}

// ---------------- converts ----------------

__global__ void cvt_x_kernel(const float* __restrict__ x, unsigned short* __restrict__ xb, int n4) {
    int i = blockIdx.x * blockDim.x + threadIdx.x;
    if (i < n4) {
        float4 v = *(const float4*)&x[i * 4];
        union { unsigned short u[4]; uint2 q; } o;
        o.u[0] = f2b(v.x); o.u[1] = f2b(v.y); o.u[2] = f2b(v.z); o.u[3] = f2b(v.w);
        *(uint2*)&xb[i * 4] = o.q;
    }
}

// Wt[n][k] = bf16(W[k][n])
__global__ void cvt_wt_kernel(const float* __restrict__ W, unsigned short* __restrict__ Wt,
                              int K, int N) {
    int idx = blockIdx.x * blockDim.x + threadIdx.x;
    if (idx < N * K) {
        int n = idx / K, k = idx - n * K;
        Wt[idx] = f2b(W[k * N + n]);
    }
}

// ---------------- bf16 MFMA GEMM: C[M][N] = A[M][K] @ Bt[N][K]^T ----------------
// 128x128 tile, 4 waves in 2x2, BK=64, 16x16x32 MFMA, XOR-swizzled LDS (T2).

template<int N, int K>
__global__ __launch_bounds__(256) void mfma_gemm_kernel(
    const unsigned short* __restrict__ A, const unsigned short* __restrict__ Bt,
    unsigned short* __restrict__ C, int M)
{
    constexpr int BK = 64;
    __shared__ unsigned short Asm[128][BK];
    __shared__ unsigned short Bsm[128][BK];
    int tid = threadIdx.x;
    int lane = tid & 63, wid = tid >> 6;
    int wr = wid >> 1, wc = wid & 1;
    int row0 = blockIdx.x * 128, col0 = blockIdx.y * 128;

    int sr = tid >> 3;
    int s8 = tid & 7;
    int sswz = s8 ^ (sr & 7);
    int fr = lane & 15;
    int g  = lane >> 4;

    f32x4 acc[4][4] = {};

    for (int k0 = 0; k0 < K; k0 += BK) {
        #pragma unroll
        for (int i = 0; i < 4; ++i) {
            int r = sr + i * 32;
            int gr = row0 + r;
            ushortx8 va = {0, 0, 0, 0, 0, 0, 0, 0};
            if (gr < M) va = *(const ushortx8*)&A[(size_t)gr * K + k0 + s8 * 8];
            *(ushortx8*)&Asm[r][sswz * 8] = va;
            ushortx8 vb = *(const ushortx8*)&Bt[(size_t)(col0 + r) * K + k0 + s8 * 8];
            *(ushortx8*)&Bsm[r][sswz * 8] = vb;
        }
        __syncthreads();
        #pragma unroll
        for (int kf = 0; kf < BK; kf += 32) {
            int sbase = kf >> 3;
            bf16x8 af[4], bfr[4];
            #pragma unroll
            for (int m = 0; m < 4; ++m) {
                int rr = wr * 64 + m * 16 + fr;
                af[m] = *(const bf16x8*)&Asm[rr][((sbase + g) ^ (fr & 7)) * 8];
            }
            #pragma unroll
            for (int n = 0; n < 4; ++n) {
                int rr = wc * 64 + n * 16 + fr;
                bfr[n] = *(const bf16x8*)&Bsm[rr][((sbase + g) ^ (fr & 7)) * 8];
            }
            #pragma unroll
            for (int m = 0; m < 4; ++m)
                #pragma unroll
                for (int n = 0; n < 4; ++n)
                    acc[m][n] = __builtin_amdgcn_mfma_f32_16x16x32_bf16(af[m], bfr[n], acc[m][n], 0, 0, 0);
        }
        __syncthreads();
    }

    // C/D layout: col = lane&15, row = (lane>>4)*4 + j
    #pragma unroll
    for (int m = 0; m < 4; ++m) {
        int rbase = row0 + wr * 64 + m * 16 + g * 4;
        #pragma unroll
        for (int j = 0; j < 4; ++j) {
            int r = rbase + j;
            if (r < M) {
                #pragma unroll
                for (int n = 0; n < 4; ++n) {
                    int c = col0 + wc * 64 + n * 16 + fr;
                    C[(size_t)r * N + c] = f2b(acc[m][n][j]);
                }
            }
        }
    }
}

// ---------------- gather (bf16 in/out), 4-way edge unroll + NT stores ----------------
// One wave per node; V = F/64 bf16 per lane (whole row per wave, coalesced).

template<int F, bool RELU>
__global__ __launch_bounds__(256) void gather_kernel(
    const int* __restrict__ ptr, const int2* __restrict__ edat,
    const float* __restrict__ dinv, const unsigned short* __restrict__ hlin,
    const float* __restrict__ bias, unsigned short* __restrict__ hout)
{
    constexpr int V = F / 64;
    int gid = blockIdx.x * blockDim.x + threadIdx.x;
    int node = gid >> 6, lane = gid & 63;
    if (node >= NV) return;
    float dc = dinv[node];
    int j0 = ptr[node], j1 = ptr[node + 1];
    float acc[V] = {};
    const unsigned short* hb = hlin + lane * V;

    int j = j0;
    for (; j + 3 < j1; j += 4) {            // 4-way unroll: 4 independent row loads in flight
        int2 e0 = edat[j],     e1 = edat[j + 1];
        int2 e2 = edat[j + 2], e3 = edat[j + 3];
        float n0 = __int_as_float(e0.y), n1 = __int_as_float(e1.y);
        float n2 = __int_as_float(e2.y), n3 = __int_as_float(e3.y);
        if constexpr (V == 4) {
            uint2 q0 = *(const uint2*)(hb + (size_t)e0.x * F);
            uint2 q1 = *(const uint2*)(hb + (size_t)e1.x * F);
            uint2 q2 = *(const uint2*)(hb + (size_t)e2.x * F);
            uint2 q3 = *(const uint2*)(hb + (size_t)e3.x * F);
            acc[0] += n0 * blo(q0.x) + n1 * blo(q1.x) + n2 * blo(q2.x) + n3 * blo(q3.x);
            acc[1] += n0 * bhi(q0.x) + n1 * bhi(q1.x) + n2 * bhi(q2.x) + n3 * bhi(q3.x);
            acc[2] += n0 * blo(q0.y) + n1 * blo(q1.y) + n2 * blo(q2.y) + n3 * blo(q3.y);
            acc[3] += n0 * bhi(q0.y) + n1 * bhi(q1.y) + n2 * bhi(q2.y) + n3 * bhi(q3.y);
        } else {
            unsigned q0 = *(const unsigned*)(hb + (size_t)e0.x * F);
            unsigned q1 = *(const unsigned*)(hb + (size_t)e1.x * F);
            unsigned q2 = *(const unsigned*)(hb + (size_t)e2.x * F);
            unsigned q3 = *(const unsigned*)(hb + (size_t)e3.x * F);
            acc[0] += n0 * blo(q0) + n1 * blo(q1) + n2 * blo(q2) + n3 * blo(q3);
            acc[1] += n0 * bhi(q0) + n1 * bhi(q1) + n2 * bhi(q2) + n3 * bhi(q3);
        }
    }
    for (; j < j1; ++j) {
        int2 e0 = edat[j];
        float n0 = __int_as_float(e0.y);
        if constexpr (V == 4) {
            uint2 q0 = *(const uint2*)(hb + (size_t)e0.x * F);
            acc[0] += n0 * blo(q0.x);
            acc[1] += n0 * bhi(q0.x);
            acc[2] += n0 * blo(q0.y);
            acc[3] += n0 * bhi(q0.y);
        } else {
            unsigned q0 = *(const unsigned*)(hb + (size_t)e0.x * F);
            acc[0] += n0 * blo(q0);
            acc[1] += n0 * bhi(q0);
        }
    }

    // self-loop (weight 2, norm dc^2) + bias (+relu); NT store keeps h table in L2
    const unsigned short* ps = hb + (size_t)node * F;
    float sw = 2.0f * dc * dc;
    if constexpr (V == 4) {
        uint2 qs = *(const uint2*)ps;
        float o0 = acc[0] + sw * blo(qs.x) + bias[lane * 4 + 0];
        float o1 = acc[1] + sw * bhi(qs.x) + bias[lane * 4 + 1];
        float o2 = acc[2] + sw * blo(qs.y) + bias[lane * 4 + 2];
        float o3 = acc[3] + sw * bhi(qs.y) + bias[lane * 4 + 3];
        if (RELU) {
            o0 = fmaxf(o0, 0.f); o1 = fmaxf(o1, 0.f);
            o2 = fmaxf(o2, 0.f); o3 = fmaxf(o3, 0.f);
        }
        union { unsigned short u[4]; unsigned long long ll; } pk;
        pk.u[0] = f2b(o0); pk.u[1] = f2b(o1); pk.u[2] = f2b(o2); pk.u[3] = f2b(o3);
        __builtin_nontemporal_store(pk.ll, (unsigned long long*)(hout + (size_t)node * F + lane * 4));
    } else {
        unsigned qs = *(const unsigned*)ps;
        float o0 = acc[0] + sw * blo(qs) + bias[lane * 2 + 0];
        float o1 = acc[1] + sw * bhi(qs) + bias[lane * 2 + 1];
        if (RELU) { o0 = fmaxf(o0, 0.f); o1 = fmaxf(o1, 0.f); }
        union { unsigned short u[2]; unsigned q; } pk;
        pk.u[0] = f2b(o0); pk.u[1] = f2b(o1);
        __builtin_nontemporal_store(pk.q, (unsigned*)(hout + (size_t)node * F + lane * 2));
    }
}

// ---------------- edge MLP via MFMA ----------------

__global__ __launch_bounds__(256) void edge_mlp_mfma_kernel(
    const int* __restrict__ pos, const int* __restrict__ neg,
    const unsigned short* __restrict__ h2, const unsigned short* __restrict__ Wl1t,
    const float* __restrict__ bl1, const float* __restrict__ Wl2,
    const float* __restrict__ bl2, float* __restrict__ out)
{
    __shared__ unsigned short Es[128][128];
    __shared__ unsigned short Ws[64][128];
    int tid = threadIdx.x;
    int lane = tid & 63, w = tid >> 6;
    int fr = lane & 15, g = lane >> 4;
    int e0 = blockIdx.x * 128;

    #pragma unroll
    for (int k = 0; k < 4; ++k) {
        int chunk = tid + k * 256;
        int row = chunk >> 4, c = chunk & 15;
        *(ushortx8*)&Ws[row][(c ^ (row & 7)) * 8] = *(const ushortx8*)&Wl1t[chunk * 8];
    }

    int et = tid >> 1, hh = tid & 1;
    int eg = e0 + et;
    int a, b;
    if (eg < EPOS) { a = pos[eg]; b = pos[EPOS + eg]; }
    else { int i = eg - EPOS; a = neg[i]; b = neg[EPOS + i]; }
    const unsigned short* pa = h2 + (size_t)a * 128 + hh * 64;
    const unsigned short* pb = h2 + (size_t)b * 128 + hh * 64;
    #pragma unroll
    for (int c8 = 0; c8 < 8; ++c8) {
        ushortx8 va = *(const ushortx8*)&pa[c8 * 8];
        ushortx8 vb = *(const ushortx8*)&pb[c8 * 8];
        ushortx8 vs = bf16add8(va, vb);
        int c = hh * 8 + c8;
        *(ushortx8*)&Es[et][(c ^ (et & 7)) * 8] = vs;
    }
    __syncthreads();

    f32x4 acc[2][4] = {};
    #pragma unroll
    for (int ks = 0; ks < 4; ++ks) {
        int c = ks * 4 + g;
        bf16x8 af[2], bfr[4];
        #pragma unroll
        for (int m = 0; m < 2; ++m) {
            int r = w * 32 + m * 16 + fr;
            af[m] = *(const bf16x8*)&Es[r][(c ^ (r & 7)) * 8];
        }
        #pragma unroll
        for (int n = 0; n < 4; ++n) {
            int r = n * 16 + fr;
            bfr[n] = *(const bf16x8*)&Ws[r][(c ^ (r & 7)) * 8];
        }
        #pragma unroll
        for (int m = 0; m < 2; ++m)
            #pragma unroll
            for (int n = 0; n < 4; ++n)
                acc[m][n] = __builtin_amdgcn_mfma_f32_16x16x32_bf16(af[m], bfr[n], acc[m][n], 0, 0, 0);
    }

    float bl2v = bl2[0];
    float b1v[4], w2v[4];
    #pragma unroll
    for (int n = 0; n < 4; ++n) {
        b1v[n] = bl1[n * 16 + fr];
        w2v[n] = Wl2[n * 16 + fr];
    }
    #pragma unroll
    for (int m = 0; m < 2; ++m) {
        float p[4];
        #pragma unroll
        for (int j = 0; j < 4; ++j) {
            float s = 0.f;
            #pragma unroll
            for (int n = 0; n < 4; ++n)
                s += fmaxf(acc[m][n][j] + b1v[n], 0.0f) * w2v[n];
            p[j] = s;
        }
        #pragma unroll
        for (int off = 1; off < 16; off <<= 1) {
            #pragma unroll
            for (int j = 0; j < 4; ++j)
                p[j] += __shfl_xor(p[j], off);
        }
        int ebase = e0 + w * 32 + m * 16 + g * 4;
        #pragma unroll
        for (int j = 0; j < 4; ++j)
            if (fr == j)
                out[ebase + j] = 1.0f / (1.0f + expf(-(p[j] + bl2v)));
    }
}

// ---------------- launch ----------------

extern "C" void kernel_launch(void* const* d_in, const int* in_sizes, int n_in,
                              void* d_out, int out_size, void* d_ws, size_t ws_size,
                              hipStream_t stream) {
    const float* x   = (const float*)d_in[0];
    const int*   tei = (const int*)d_in[1];
    const int*   pos = (const int*)d_in[2];
    const int*   neg = (const int*)d_in[3];
    const float* W1  = (const float*)d_in[4];
    const float* b1  = (const float*)d_in[5];
    const float* W2  = (const float*)d_in[6];
    const float* b2  = (const float*)d_in[7];
    const float* Wl1 = (const float*)d_in[8];
    const float* bl1 = (const float*)d_in[9];
    const float* Wl2 = (const float*)d_in[10];
    const float* bl2 = (const float*)d_in[11];
    float* out = (float*)d_out;

    // workspace (4B-word offsets)
    float* fws = (float*)d_ws;
    int*   iws = (int*)d_ws;
    unsigned short* usws = (unsigned short*)d_ws;
    float* dinv     = fws;                         // [50000]
    int*   deg      = iws + 50000;                 // [50000]
    int*   ptr      = iws + 100000;                // [50001]
    int*   cursor   = iws + 150002;                // [50000]
    int2*  edat     = (int2*)(iws + 200064);       // [800000] int2 -> ends 1800064
    int*   partials = iws + 1800064;               // [64]
    unsigned short* w1t  = usws + 2ull * 1800192;  // [256*256]
    unsigned short* w2t  = usws + 2ull * 1832960;  // [128*256]
    unsigned short* wl1t = usws + 2ull * 1849344;  // [64*128]
    unsigned short* bufX = usws + 2ull * 1853504;  // 12.8M ushorts: xb, then h2lin
    unsigned short* bufL16 = usws + 2ull * 8253504;  // h1lin bf16, then h2 bf16
    unsigned short* bufH = usws + 2ull * 14653504;   // h1 bf16

    hipMemsetAsync(deg, 0, NV * sizeof(int), stream);

    deg_kernel<<<(ETR + 255) / 256, 256, 0, stream>>>(tei, deg);
    partial_kernel<<<49, 1024, 0, stream>>>(deg, partials);
    ptr_kernel<<<49, 1024, 0, stream>>>(deg, partials, ptr, cursor, dinv);
    fill_kernel<<<(ETR + 255) / 256, 256, 0, stream>>>(tei, dinv, cursor, edat);

    cvt_x_kernel<<<(NV * 256 / 4 + 255) / 256, 256, 0, stream>>>(x, bufX, NV * 256 / 4);
    cvt_wt_kernel<<<(256 * 256 + 255) / 256, 256, 0, stream>>>(W1, w1t, 256, 256);
    cvt_wt_kernel<<<(128 * 256 + 255) / 256, 256, 0, stream>>>(W2, w2t, 256, 128);
    cvt_wt_kernel<<<(64 * 128 + 255) / 256, 256, 0, stream>>>(Wl1, wl1t, 128, 64);

    // layer 1
    mfma_gemm_kernel<256, 256><<<dim3(391, 2), 256, 0, stream>>>(bufX, w1t, bufL16, NV);
    gather_kernel<256, true><<<(NV * 64) / 256, 256, 0, stream>>>(ptr, edat, dinv, bufL16, b1, bufH);

    // layer 2 (h2lin overwrites bufX; h2 bf16 overwrites bufL16)
    mfma_gemm_kernel<128, 256><<<dim3(391, 1), 256, 0, stream>>>(bufH, w2t, bufX, NV);
    gather_kernel<128, false><<<(NV * 64) / 256, 256, 0, stream>>>(ptr, edat, dinv, bufX, b2, bufL16);

    // edge MLP head (MFMA)
    edge_mlp_mfma_kernel<<<ETEST / 128, 256, 0, stream>>>(pos, neg, bufL16, wl1t, bl1, Wl2, bl2, out);
}